// Round 4
// baseline (76.549 us; speedup 1.0000x reference)
//
#include <hip/hip_runtime.h>
#include <math.h>

// Sizes fixed by the reference.
#define SIDE 32
#define BSZ  16
#define DIM  1024
#define DPB  16        // d-channels per block (64B global granule)
#define THREADS 512    // 16 half-waves: hw = d-index 0..15, lanes = rows
#define M_CHAIN 2      // images (b's) chained per lane -> 96 steps
// LDS layout: row i occupies floats [i*1024, i*1024+1024): 64 E-slots x 16 d.
#define ROWF    1024
#define XFLOATS (32 * ROWF)          // 32768 floats
#define PADF    512                  // overrun pad for invalid-lane reads
#define DUMPOFF (XFLOATS + PADF)     // dump slots for invalid-lane writes
#define LDSF    (DUMPOFF + THREADS)  // 33792 floats
#define LDSB    (LDSF * 4)           // 135168 B (dynamic LDS, <160KB)

__device__ __forceinline__ float sigmoidf_(float v) {
    return __builtin_amdgcn_rcpf(1.0f + __expf(-v));
}

// lane n <- lane n-1 across the wave (lane 0 -> 0), pure VALU:
// v_mov_b32_dpp wave_shr:1 (ctrl 0x138), ~2cy vs ~120cy ds_bpermute.
__device__ __forceinline__ float dpp_up1(float v) {
    return __int_as_float(__builtin_amdgcn_update_dpp(
        0, __float_as_int(v), 0x138, 0xF, 0xF, true));
}

extern __shared__ float xs[];

// 2D SSM recurrence (== reference FFT path by linearity/causality):
//   v[i,j] = a2*h[i-1,j] + a1*v[i-1,j] + b2*x[i,j]
//   h[i,j] = a1*h[i,j-1] + a2*v[i,j-1] + b1*x[i,j]
//   out = silu(<h,C1s>+<v,C2s> + x*omega)
//
// Parallelogram-chained anti-diagonal wavefront: lane = row i; at step ts
// it processes column j=(ts-i)&31 of image m=(ts-i)>>5 (chain of 2 b's).
// Own-state resets when (ts-i)&31==0 (new image); neighbor (h,v)[i-1,j]
// arrives via one wave_shr:1 DPP per state word (lane i-1 computed the
// same image/column at ts-1 -- the chain is seamless). Lane efficiency
// 64/95 vs 32/63 unchained. Memory is woven into the step loop in 6
// periods of 16 steps: stage slot p+1, compute, drain slot p-3, one
// barrier per period -> HBM traffic spread across the whole kernel.
__global__ __launch_bounds__(THREADS, 1) void ssm2d_kernel(
    const float* __restrict__ x,
    const float* __restrict__ A1, const float* __restrict__ A2,
    const float* __restrict__ B1, const float* __restrict__ B2,
    const float* __restrict__ C1, const float* __restrict__ C2,
    const float* __restrict__ omega,
    float* __restrict__ out)
{
    const int bx   = blockIdx.x;       // 0..511
    const int dgrp = bx & 63;
    const int bp   = bx >> 6;          // 0..7
    const int d0   = dgrp * DPB;
    const int b0   = bp * 2;
    const int t    = threadIdx.x;

    // ---- staging/drain thread mapping: (i, j') = (t&31, t>>5) ----
    const int si  = t & 31;
    const int sj  = t >> 5;            // 0..15
    const int sHi = (si >> 2) & 3, sLo = si & 3;
    const int sq0 = (0 ^ sHi) << 2, sq1 = (1 ^ sHi) << 2;
    const int sq2 = (2 ^ sHi) << 2, sq3 = (3 ^ sHi) << 2;
    const int r0 = 0 ^ sLo, r1 = 1 ^ sLo, r2 = 2 ^ sLo, r3 = 3 ^ sLo;

    // global flat offset of (s=32*si+jj, b, d0) for slot q
#define GOFF(Q) ((((size_t)(32 * si + (((Q) & 1) << 4) + sj)) * BSZ \
                   + (size_t)(b0 + ((Q) >> 1))) * DIM + d0)
    // LDS float base of (row si, E = 16q+sj)
#define LBASE(Q) (si * ROWF + ((((Q) << 4) + sj) << 4))

#define STAGE_LOAD(Q, A0_, A1_, A2_, A3_) {                      \
        const float* gp = x + GOFF(Q);                           \
        A0_ = *reinterpret_cast<const float4*>(gp);              \
        A1_ = *reinterpret_cast<const float4*>(gp + 4);          \
        A2_ = *reinterpret_cast<const float4*>(gp + 8);          \
        A3_ = *reinterpret_cast<const float4*>(gp + 12); }

#define STAGE_WRITE(Q, A0_, A1_, A2_, A3_) {                     \
        const int lb = LBASE(Q);                                 \
        xs[lb+sq0+r0]=A0_.x; xs[lb+sq0+r1]=A0_.y;                \
        xs[lb+sq0+r2]=A0_.z; xs[lb+sq0+r3]=A0_.w;                \
        xs[lb+sq1+r0]=A1_.x; xs[lb+sq1+r1]=A1_.y;                \
        xs[lb+sq1+r2]=A1_.z; xs[lb+sq1+r3]=A1_.w;                \
        xs[lb+sq2+r0]=A2_.x; xs[lb+sq2+r1]=A2_.y;                \
        xs[lb+sq2+r2]=A2_.z; xs[lb+sq2+r3]=A2_.w;                \
        xs[lb+sq3+r0]=A3_.x; xs[lb+sq3+r1]=A3_.y;                \
        xs[lb+sq3+r2]=A3_.z; xs[lb+sq3+r3]=A3_.w; }

#define DRAIN(Q) {                                               \
        const int lb = LBASE(Q);                                 \
        float4 S0, S1, S2, S3;                                   \
        S0.x=xs[lb+sq0+r0]; S0.y=xs[lb+sq0+r1];                  \
        S0.z=xs[lb+sq0+r2]; S0.w=xs[lb+sq0+r3];                  \
        S1.x=xs[lb+sq1+r0]; S1.y=xs[lb+sq1+r1];                  \
        S1.z=xs[lb+sq1+r2]; S1.w=xs[lb+sq1+r3];                  \
        S2.x=xs[lb+sq2+r0]; S2.y=xs[lb+sq2+r1];                  \
        S2.z=xs[lb+sq2+r2]; S2.w=xs[lb+sq2+r3];                  \
        S3.x=xs[lb+sq3+r0]; S3.y=xs[lb+sq3+r1];                  \
        S3.z=xs[lb+sq3+r2]; S3.w=xs[lb+sq3+r3];                  \
        float* op = out + GOFF(Q);                               \
        *reinterpret_cast<float4*>(op)      = S0;                \
        *reinterpret_cast<float4*>(op + 4)  = S1;                \
        *reinterpret_cast<float4*>(op + 8)  = S2;                \
        *reinterpret_cast<float4*>(op + 12) = S3; }

    // ---- compute-lane mapping: half-wave hw = d-index, lane&31 = row ----
    const int lane = t & 63;
    const int wv   = t >> 6;
    const int hw   = 2 * wv + (lane >> 5);   // 0..15
    const int i    = lane & 31;              // row
    const int d    = d0 + hw;
    const int cHi  = (i >> 2) & 3, cLo = i & 3;
    const int dposf = (((hw >> 2) ^ cHi) << 2) + ((hw & 3) ^ cLo);
    float* xp = xs + 1008 * i + dposf;       // read/write addr = xp + 16*ts
    float* dumpp = xs + DUMPOFF + t;

    float a1c0, a1c1, a2c0, a2c1, b1c0, b1c1, b2c0, b2c1;
    float c1s0, c1s1, c2s0, c2s1;
    {
        a1c0 = sigmoidf_(A1[d*2+0]) * 0.5f;  a1c1 = sigmoidf_(A1[d*2+1]) * 0.5f;
        a2c0 = sigmoidf_(A2[d*2+0]) * 0.5f;  a2c1 = sigmoidf_(A2[d*2+1]) * 0.5f;
        b1c0 = sigmoidf_(B1[d*2+0]) * 0.5f;  b1c1 = sigmoidf_(B1[d*2+1]) * 0.5f;
        b2c0 = sigmoidf_(B2[d*2+0]) * 0.5f;  b2c1 = sigmoidf_(B2[d*2+1]) * 0.5f;
        const float sc = 0.70710678118654752f;
        c1s0 = C1[d*2+0] * sc;  c1s1 = C1[d*2+1] * sc;
        c2s0 = C2[d*2+0] * sc;  c2s1 = C2[d*2+1] * sc;
    }
    const float om = omega[d];
    // top-lane (row 0 of each half-wave) neighbor-intake zeroing, folded
    // into coefficient copies: no per-step cndmask needed.
    const float a1z0 = (i == 0) ? 0.f : a1c0, a1z1 = (i == 0) ? 0.f : a1c1;
    const float a2z0 = (i == 0) ? 0.f : a2c0, a2z1 = (i == 0) ? 0.f : a2c1;

    float h0 = 0.f, h1 = 0.f, v0 = 0.f, v1 = 0.f;

#define STEP(TS, XV) {                                               \
        const float hu0 = dpp_up1(h0), hu1 = dpp_up1(h1);            \
        const float vu0 = dpp_up1(v0), vu1 = dpp_up1(v1);            \
        const int   e   = (TS) - i;                                  \
        const bool  valid = ((unsigned)e < (unsigned)(32*M_CHAIN));  \
        const bool  reset = ((e & 31) == 0);                         \
        const float xv  = (XV);                                      \
        const float t10 = b1c0 * xv, t11 = b1c1 * xv;                \
        const float hf0 = fmaf(a1c0, h0, fmaf(a2c0, v0, t10));       \
        const float hf1 = fmaf(a1c1, h1, fmaf(a2c1, v1, t11));      \
        const float hn0 = reset ? t10 : hf0;                         \
        const float hn1 = reset ? t11 : hf1;                         \
        const float vn0 = fmaf(a2z0, hu0, fmaf(a1z0, vu0, b2c0*xv)); \
        const float vn1 = fmaf(a2z1, hu1, fmaf(a1z1, vu1, b2c1*xv)); \
        float y = hn0 * c1s0; y = fmaf(hn1, c1s1, y);                \
        y = fmaf(vn0, c2s0, y); y = fmaf(vn1, c2s1, y);              \
        const float z = fmaf(xv, om, y);                             \
        const float o = z * sigmoidf_(z);                            \
        float* wp = valid ? (xp + 16 * (TS)) : dumpp;                \
        *wp = o;                                                     \
        h0 = hn0; h1 = hn1; v0 = vn0; v1 = vn1; }

#define PERIOD_STEPS(P)                                       \
    STEP(16*(P)+0,  xq0); xq0 = xp[16*(16*(P)+3)];            \
    STEP(16*(P)+1,  xq1); xq1 = xp[16*(16*(P)+4)];            \
    STEP(16*(P)+2,  xq2); xq2 = xp[16*(16*(P)+5)];            \
    STEP(16*(P)+3,  xq0); xq0 = xp[16*(16*(P)+6)];            \
    STEP(16*(P)+4,  xq1); xq1 = xp[16*(16*(P)+7)];            \
    STEP(16*(P)+5,  xq2); xq2 = xp[16*(16*(P)+8)];            \
    STEP(16*(P)+6,  xq0); xq0 = xp[16*(16*(P)+9)];            \
    STEP(16*(P)+7,  xq1); xq1 = xp[16*(16*(P)+10)];           \
    STEP(16*(P)+8,  xq2); xq2 = xp[16*(16*(P)+11)];           \
    STEP(16*(P)+9,  xq0); xq0 = xp[16*(16*(P)+12)];           \
    STEP(16*(P)+10, xq1); xq1 = xp[16*(16*(P)+13)];           \
    STEP(16*(P)+11, xq2); xq2 = xp[16*(16*(P)+14)];           \
    STEP(16*(P)+12, xq0); xq0 = xp[16*(16*(P)+15)];           \
    STEP(16*(P)+13, xq1);                                     \
    STEP(16*(P)+14, xq2);                                     \
    STEP(16*(P)+15, xq0);

    // ---- prologue: stage slot 0 ----
    {
        float4 A0_, A1_, A2_, A3_;
        STAGE_LOAD(0, A0_, A1_, A2_, A3_);
        STAGE_WRITE(0, A0_, A1_, A2_, A3_);
    }

    // ---- 6 periods of 16 steps ----
#pragma unroll
    for (int p = 0; p < 6; ++p) {
        __syncthreads();
        float4 A0_, A1_, A2_, A3_;
        if (p <= 2) STAGE_LOAD(p + 1, A0_, A1_, A2_, A3_);
        // prefetch pipeline (3 deep), all offsets compile-time immediates
        float xq0 = xp[16 * (16 * p + 0)];
        float xq1 = xp[16 * (16 * p + 1)];
        float xq2 = xp[16 * (16 * p + 2)];
        PERIOD_STEPS(p);
        if (p >= 3) DRAIN(p - 3);
        if (p <= 2) STAGE_WRITE(p + 1, A0_, A1_, A2_, A3_);
    }
    __syncthreads();
    DRAIN(3);
}

extern "C" void kernel_launch(void* const* d_in, const int* in_sizes, int n_in,
                              void* d_out, int out_size, void* d_ws, size_t ws_size,
                              hipStream_t stream) {
    const float* x     = (const float*)d_in[0];
    const float* A1    = (const float*)d_in[1];
    const float* A2    = (const float*)d_in[2];
    const float* B1    = (const float*)d_in[3];
    const float* B2    = (const float*)d_in[4];
    const float* C1    = (const float*)d_in[5];
    const float* C2    = (const float*)d_in[6];
    const float* omega = (const float*)d_in[7];
    float* out = (float*)d_out;

    (void)hipFuncSetAttribute(reinterpret_cast<const void*>(ssm2d_kernel),
                              hipFuncAttributeMaxDynamicSharedMemorySize, LDSB);

    dim3 grid(64 * (BSZ / M_CHAIN));   // 64 d-groups x 8 b-pairs = 512 blocks
    dim3 block(THREADS);
    hipLaunchKernelGGL(ssm2d_kernel, grid, block, LDSB, stream,
                       x, A1, A2, B1, B2, C1, C2, omega, out);
}

// Round 5
// 45.296 us; speedup vs baseline: 1.6900x; 1.6900x over previous
//
#include <hip/hip_runtime.h>
#include <math.h>

// Sizes fixed by the reference.
#define BSZ  16
#define DIM  1024
#define DPB  16        // d-channels per block (64B global granule)
#define THREADS 512    // 8 waves; each half-wave (32 lanes) owns one (b,d) image
#define SSTRIDE 17     // LDS float-stride per s-cell: 17*31=527==15 (mod 32),
                       // gcd(15,32)=1 -> compute reads hit all 32 banks once
#define LDSF   17472   // covers max idx 17*1026+15 (=17457) incl. prefetch overrun
#define LDSB   (LDSF * 4)   // 69888 B dynamic LDS -> 2 blocks/CU

__device__ __forceinline__ float sigmoidf_(float v) {
    return __builtin_amdgcn_rcpf(1.0f + __expf(-v));
}

extern __shared__ float xs[];

// 2D SSM run as the recurrence directly on x (== causal conv with the impulse
// response == reference FFT path, by linearity/shift-invariance/causality):
//   v[i,j] = a2*h[i-1,j] + a1*v[i-1,j] + b2*x[i,j]
//   h[i,j] = a1*h[i,j-1] + a2*v[i,j-1] + b1*x[i,j]
//   y[i,j] = <h,C1*s> + <v,C2*s>;  out = silu(y + x*omega)
//
// Anti-diagonal wavefront: lane = row i, step ts sweeps anti-diagonals,
// j = ts - i.  h-update uses only the lane's own previous-step registers;
// v-update needs (h,v)[i-1,j] (lane i-1's step ts-1 state), folded directly
// into the FMA via v_fmac_f32_dpp wave_shr:1 (DPP on src0) -- no separate
// mov_dpp, no cndmask: lane0 intake is zeroed by bound_ctrl:0, lane32 (row 0
// of the half-wave's second image... lanes 32..63 are an independent image)
// is zeroed by per-lane coefficients a1z/a2z = 0 at i==0.
// Pre-valid lanes keep exactly-zero state: xv is masked to 0, so h,v stay 0,
// and their upstream neighbor is also still zero at the time they start.
__global__ __launch_bounds__(THREADS, 1) void ssm2d_kernel(
    const float* __restrict__ x,
    const float* __restrict__ A1, const float* __restrict__ A2,
    const float* __restrict__ B1, const float* __restrict__ B2,
    const float* __restrict__ C1, const float* __restrict__ C2,
    const float* __restrict__ omega,
    float* __restrict__ out)
{
    const int bx = blockIdx.x;     // 0..1023
    const int b  = bx >> 6;        // 0..15
    const int d0 = (bx & 63) * DPB;
    const int t  = threadIdx.x;

    // ---- per-lane channel & coefficients (issued early, overlap staging) ----
    const int lane = t & 63;
    const int wv   = t >> 6;               // wave 0..7
    const int dd   = 2 * wv + (lane >> 5); // image (d-index) 0..15
    const int i    = lane & 31;            // row owned by this lane
    const int d    = d0 + dd;

    const float2 fA1 = *reinterpret_cast<const float2*>(A1 + 2 * d);
    const float2 fA2 = *reinterpret_cast<const float2*>(A2 + 2 * d);
    const float2 fB1 = *reinterpret_cast<const float2*>(B1 + 2 * d);
    const float2 fB2 = *reinterpret_cast<const float2*>(B2 + 2 * d);
    const float2 fC1 = *reinterpret_cast<const float2*>(C1 + 2 * d);
    const float2 fC2 = *reinterpret_cast<const float2*>(C2 + 2 * d);
    const float  om  = omega[d];

    const float a1c0 = sigmoidf_(fA1.x) * 0.5f, a1c1 = sigmoidf_(fA1.y) * 0.5f;
    const float a2c0 = sigmoidf_(fA2.x) * 0.5f, a2c1 = sigmoidf_(fA2.y) * 0.5f;
    const float b1c0 = sigmoidf_(fB1.x) * 0.5f, b1c1 = sigmoidf_(fB1.y) * 0.5f;
    const float b2c0 = sigmoidf_(fB2.x) * 0.5f, b2c1 = sigmoidf_(fB2.y) * 0.5f;
    const float sc   = 0.70710678118654752f;
    const float c1s0 = fC1.x * sc, c1s1 = fC1.y * sc;
    const float c2s0 = fC2.x * sc, c2s1 = fC2.y * sc;
    // neighbor-intake coefficients, zeroed at the top row of each image
    const float a1z0 = (i == 0) ? 0.f : a1c0, a1z1 = (i == 0) ? 0.f : a1c1;
    const float a2z0 = (i == 0) ? 0.f : a2c0, a2z1 = (i == 0) ? 0.f : a2c1;

    // ---- stage x into LDS (coalesced float4; idx = 17*s + dd) ----
    const float* xb = x + (size_t)b * DIM + d0;
    float4 L[8];
    #pragma unroll
    for (int k = 0; k < 8; ++k) {
        const int g = t + k * THREADS;       // 0..4095
        const int s = g >> 2;
        const int q = g & 3;
        L[k] = *reinterpret_cast<const float4*>(
            xb + (size_t)s * (BSZ * DIM) + 4 * q);
    }
    #pragma unroll
    for (int k = 0; k < 8; ++k) {
        const int g = t + k * THREADS;
        const int s = g >> 2;
        const int q = g & 3;
        float* p = xs + SSTRIDE * s + 4 * q; // bank 17s+4q+r: <=2-way (free)
        p[0] = L[k].x; p[1] = L[k].y; p[2] = L[k].z; p[3] = L[k].w;
    }

    __syncthreads();

    // ---- anti-diagonal recurrence, 63 fully-unrolled steps ----
    // addr(ts) = 527*i + dd + 17*ts : linear -> immediate ds offsets.
    float* rp = xs + 527 * i + dd;

    float h0 = 0.f, h1 = 0.f, v0 = 0.f, v1 = 0.f;
    // 3-deep x prefetch: issue-to-use ~3 steps (>LDS latency)
    float xq0 = rp[0 * SSTRIDE];
    float xq1 = rp[1 * SSTRIDE];
    float xq2 = rp[2 * SSTRIDE];

#define SSTEP(TS, XQ) do {                                                   \
        const bool  valid = ((unsigned)((TS) - i) < 32u);                    \
        const float xv    = valid ? (XQ) : 0.f;                              \
        const float t10 = b1c0 * xv, t11 = b1c1 * xv;                        \
        const float hn0 = fmaf(a1c0, h0, fmaf(a2c0, v0, t10));               \
        const float hn1 = fmaf(a1c1, h1, fmaf(a2c1, v1, t11));               \
        float vn0 = b2c0 * xv, vn1 = b2c1 * xv;                              \
        asm("s_nop 1\n\t"                                                    \
            "v_fmac_f32_dpp %0, %2, %6 wave_shr:1 row_mask:0xf bank_mask:0xf bound_ctrl:0\n\t" \
            "v_fmac_f32_dpp %1, %3, %7 wave_shr:1 row_mask:0xf bank_mask:0xf bound_ctrl:0\n\t" \
            "v_fmac_f32_dpp %0, %4, %8 wave_shr:1 row_mask:0xf bank_mask:0xf bound_ctrl:0\n\t" \
            "v_fmac_f32_dpp %1, %5, %9 wave_shr:1 row_mask:0xf bank_mask:0xf bound_ctrl:0"     \
            : "+v"(vn0), "+v"(vn1)                                           \
            : "v"(h0), "v"(h1), "v"(v0), "v"(v1),                            \
              "v"(a2z0), "v"(a2z1), "v"(a1z0), "v"(a1z1));                   \
        float y = hn0 * c1s0;                                                \
        y = fmaf(hn1, c1s1, y);                                              \
        y = fmaf(vn0, c2s0, y);                                              \
        y = fmaf(vn1, c2s1, y);                                              \
        const float z = fmaf(xv, om, y);                                     \
        const float o = z * sigmoidf_(z);                                    \
        if (valid) rp[SSTRIDE * (TS)] = o;                                   \
        h0 = hn0; h1 = hn1; v0 = vn0; v1 = vn1;                              \
    } while (0)

    #pragma unroll
    for (int ts = 0; ts < 63; ts += 3) {
        SSTEP(ts + 0, xq0); xq0 = rp[SSTRIDE * (ts + 3)];  // overrun -> pad
        SSTEP(ts + 1, xq1); xq1 = rp[SSTRIDE * (ts + 4)];
        SSTEP(ts + 2, xq2); xq2 = rp[SSTRIDE * (ts + 5)];
    }
#undef SSTEP

    __syncthreads();

    // ---- coalesced float4 store-out (mirror of staging) ----
    float* ob = out + (size_t)b * DIM + d0;
    #pragma unroll
    for (int k = 0; k < 8; ++k) {
        const int g = t + k * THREADS;
        const int s = g >> 2;
        const int q = g & 3;
        const float* p = xs + SSTRIDE * s + 4 * q;
        float4 v;
        v.x = p[0]; v.y = p[1]; v.z = p[2]; v.w = p[3];
        *reinterpret_cast<float4*>(ob + (size_t)s * (BSZ * DIM) + 4 * q) = v;
    }
}

extern "C" void kernel_launch(void* const* d_in, const int* in_sizes, int n_in,
                              void* d_out, int out_size, void* d_ws, size_t ws_size,
                              hipStream_t stream) {
    const float* x     = (const float*)d_in[0];
    const float* A1    = (const float*)d_in[1];
    const float* A2    = (const float*)d_in[2];
    const float* B1    = (const float*)d_in[3];
    const float* B2    = (const float*)d_in[4];
    const float* C1    = (const float*)d_in[5];
    const float* C2    = (const float*)d_in[6];
    const float* omega = (const float*)d_in[7];
    float* out = (float*)d_out;

    (void)hipFuncSetAttribute(reinterpret_cast<const void*>(ssm2d_kernel),
                              hipFuncAttributeMaxDynamicSharedMemorySize, LDSB);

    dim3 grid(BSZ * (DIM / DPB));   // 1024 blocks
    dim3 block(THREADS);
    hipLaunchKernelGGL(ssm2d_kernel, grid, block, LDSB, stream,
                       x, A1, A2, B1, B2, C1, C2, omega, out);
}